// Round 7
// baseline (424.975 us; speedup 1.0000x reference)
//
#include <hip/hip_runtime.h>
#include <hip/hip_bf16.h>

#define N_ATOMS 100000
#define N_PAIRS 2000000
#define N_EMB 30
#define N_DIST 100
#define N_HID 60

#define TE 64                       // edges per tile
#define NTILES (N_PAIRS / TE)       // 31250 exact
#define EBLOCKS 768

typedef short bf16x8 __attribute__((ext_vector_type(8)));
typedef float f32x4 __attribute__((ext_vector_type(4)));

__device__ __forceinline__ ushort f2bf(float f) {
    __hip_bfloat16 h = __float2bfloat16(f);
    return __builtin_bit_cast(ushort, h);
}
__device__ __forceinline__ float bf2f(ushort u) {
    __hip_bfloat16 h = __builtin_bit_cast(__hip_bfloat16, u);
    return __bfloat162float(h);
}
__device__ __forceinline__ float fast_tanh(float x) {
    float e = __expf(2.0f * x);
    return 1.0f - 2.0f / (e + 1.0f);
}

// ---------------- Kernel A: per-atom hidden + output init ----------------
// writes ah in bf16 (edge kernel's gather table, L2-resident at 12 MB)
__global__ __launch_bounds__(256) void atom_kernel(
    const float* __restrict__ af, const float* __restrict__ W_cf,
    const float* __restrict__ W_fc, const float* __restrict__ b_cf,
    const float* __restrict__ b_df, ushort* __restrict__ ah_bf,
    float* __restrict__ out)
{
    __shared__ __align__(16) float ah_lds[4][N_HID];
    const int wave = threadIdx.x >> 6;
    const int lane = threadIdx.x & 63;
    const int n = blockIdx.x * 4 + wave;

    float ahv = 0.f;
    if (lane < N_HID) {
        ahv = b_cf[lane];
        #pragma unroll
        for (int k = 0; k < N_EMB; ++k)
            ahv = fmaf(af[(size_t)n * N_EMB + k], W_cf[k * N_HID + lane], ahv);
        ah_bf[(size_t)n * N_HID + lane] = f2bf(ahv);
        ah_lds[wave][lane] = ahv * b_df[lane];
    }
    __syncthreads();
    if (lane < N_EMB) {
        float s = 0.f;
        #pragma unroll
        for (int h = 0; h < N_HID; ++h)
            s = fmaf(ah_lds[wave][h], W_fc[h * N_EMB + lane], s);
        out[(size_t)n * N_EMB + lane] =
            af[(size_t)n * N_EMB + lane] - fast_tanh(s);
    }
}

// ---------------- Kernel B: fused MFMA edge pipeline ----------------
// 2 barriers/tile, single A buffer (pf[] regs are the 2nd stage),
// ah gather pipelined one full tile ahead.
__global__ __launch_bounds__(256, 3) void edge_kernel(
    const float* __restrict__ dist,
    const int* __restrict__ mi, const int* __restrict__ mj,
    const float* __restrict__ W_df, const float* __restrict__ W_fc,
    const float* __restrict__ b_df, const ushort* __restrict__ ah_bf,
    float* out)
{
    __shared__ ushort A_lds[TE * 136];        // 17408 B
    __shared__ ushort T_lds[TE * 72];         // 9216 B
    __shared__ ushort S_lds[32 * 72];         // 4608 B  (S^T: [f][edge])
    __shared__ int    mis[2][TE], mjs[2][TE]; // 1024 B
    __shared__ int    seg_lds[TE];            // 256 B
    __shared__ int    seg_atom[TE];           // 256 B

    const int tid = threadIdx.x;
    const int wv = tid >> 6, lane = tid & 63;
    const int l4 = lane >> 4, ln = lane & 15;
    const int h1 = wv * 16 + ln;              // stage-1 hid col for this lane
    const int srow = tid >> 2, sc4 = tid & 3; // staging: row, f4-phase

    // ---- one-time weight fragments ----
    bf16x8 wdf_hi[4], wdf_lo[4];              // B-frag: k = ks*32 + l4*8 + i, n = h1
    #pragma unroll
    for (int ks = 0; ks < 4; ++ks) {
        #pragma unroll
        for (int i = 0; i < 8; ++i) {
            int k = ks * 32 + l4 * 8 + i;
            float f = (k < N_DIST && h1 < N_HID) ? W_df[k * N_HID + h1] : 0.f;
            ushort hi = f2bf(f);
            wdf_hi[ks][i] = (short)hi;
            wdf_lo[ks][i] = (short)f2bf(f - bf2f(hi));
        }
    }
    bf16x8 wfc[2][2];                         // [nf][ks]
    #pragma unroll
    for (int nf = 0; nf < 2; ++nf) {
        #pragma unroll
        for (int ks = 0; ks < 2; ++ks) {
            #pragma unroll
            for (int i = 0; i < 8; ++i) {
                int k = ks * 32 + l4 * 8 + i;
                int n = nf * 16 + ln;
                float f = (k < N_HID && n < N_EMB) ? W_fc[k * N_EMB + n] : 0.f;
                wfc[nf][ks][i] = (short)f2bf(f);
            }
        }
    }
    const float bdf1 = (h1 < N_HID) ? b_df[h1] : 0.f;

    // zero A pad columns [100..136) once (never rewritten)
    for (int idx = tid; idx < TE * 36; idx += 256) {
        int r = idx / 36, c = 100 + idx % 36;
        A_lds[r * 136 + c] = 0;
    }

    const int t0 = (int)(((long long)blockIdx.x * NTILES) / EBLOCKS);
    const int t1 = (int)(((long long)(blockIdx.x + 1) * NTILES) / EBLOCKS);

    f32x4 pf[7];
    int pmi = 0, pmj = 0;

    // per-thread mapping: row srow; f4 index c = sc4 + 4k (k=0..5; k==6 only sc4==0)
    auto stage_issue = [&](int t) {
        const f32x4* src = (const f32x4*)(dist + (size_t)t * TE * N_DIST) + (srow * 25 + sc4);
        #pragma unroll
        for (int k = 0; k < 6; ++k)
            pf[k] = __builtin_nontemporal_load(src + 4 * k);
        if (sc4 == 0) pf[6] = __builtin_nontemporal_load(src + 24);
        if (tid < TE) {
            pmi = mi[t * TE + tid];
            pmj = mj[t * TE + tid];
        }
    };
    auto stage_write = [&](int buf) {
        ushort* dst = &A_lds[srow * 136 + sc4 * 4];
        #pragma unroll
        for (int k = 0; k < 7; ++k) {
            if (k < 6 || sc4 == 0) {
                f32x4 v = pf[k];
                ushort4 pk2;
                pk2.x = f2bf(v[0]); pk2.y = f2bf(v[1]);
                pk2.z = f2bf(v[2]); pk2.w = f2bf(v[3]);
                *(ushort4*)(dst + 16 * k) = pk2;
            }
        }
        if (tid < TE) { mis[buf][tid] = pmi; mjs[buf][tid] = pmj; }
    };

    float ahg[4][4];
    auto gather = [&](int buf) {
        #pragma unroll
        for (int m = 0; m < 4; ++m) {
            #pragma unroll
            for (int r = 0; r < 4; ++r) {
                int el = 16 * m + l4 * 4 + r;
                int j = mjs[buf][el];
                ahg[m][r] = (h1 < N_HID) ? bf2f(ah_bf[(size_t)j * N_HID + h1]) : 0.f;
            }
        }
    };

    // prologue: stage tile t0, prefetch its ah rows
    stage_issue(t0);
    stage_write(0);
    __syncthreads();
    gather(0);

    int cur = 0;
    for (int t = t0; t < t1; ++t) {
        const bool hasnext = (t + 1 < t1);
        if (hasnext) stage_issue(t + 1);      // lands during this tile's compute

        // ---- stage-1 MFMA: 64 edges x 16 hids (hi/lo split) ----
        f32x4 acc1[4] = {{0,0,0,0},{0,0,0,0},{0,0,0,0},{0,0,0,0}};
        #pragma unroll
        for (int ks = 0; ks < 4; ++ks) {
            #pragma unroll
            for (int m = 0; m < 4; ++m) {
                bf16x8 a = *(const bf16x8*)&A_lds[(16 * m + ln) * 136 + ks * 32 + l4 * 8];
                acc1[m] = __builtin_amdgcn_mfma_f32_16x16x32_bf16(a, wdf_hi[ks], acc1[m], 0, 0, 0);
                acc1[m] = __builtin_amdgcn_mfma_f32_16x16x32_bf16(a, wdf_lo[ks], acc1[m], 0, 0, 0);
            }
        }

        // ---- t = (dh + b_df) * ah (prefetched last tile) -> bf16 -> T_lds ----
        #pragma unroll
        for (int m = 0; m < 4; ++m) {
            #pragma unroll
            for (int r = 0; r < 4; ++r) {
                int row = 16 * m + l4 * 4 + r;
                float tv = (acc1[m][r] + bdf1) * ahg[m][r];
                T_lds[row * 72 + h1] = (h1 < N_HID) ? f2bf(tv) : (ushort)0;
            }
        }
        __syncthreads();   // B2: T ready; A-readers (MFMA1) done

        // ---- stage-2 MFMA: 16 edges x 32 f ----
        f32x4 acc2[2] = {{0,0,0,0},{0,0,0,0}};
        #pragma unroll
        for (int ks = 0; ks < 2; ++ks) {
            bf16x8 a2 = *(const bf16x8*)&T_lds[(16 * wv + ln) * 72 + ks * 32 + l4 * 8];
            #pragma unroll
            for (int nf = 0; nf < 2; ++nf)
                acc2[nf] = __builtin_amdgcn_mfma_f32_16x16x32_bf16(a2, wfc[nf][ks], acc2[nf], 0, 0, 0);
        }
        // tanh -> S^T (bf16); rows f>=30 exact zeros
        #pragma unroll
        for (int nf = 0; nf < 2; ++nf) {
            #pragma unroll
            for (int r = 0; r < 4; ++r) {
                int f = nf * 16 + ln;
                int e = 16 * wv + l4 * 4 + r;
                S_lds[f * 72 + e] = f2bf(fast_tanh(acc2[nf][r]));
            }
        }

        // write next tile's A + metadata (A-readers done since B2; next reads after B3)
        if (hasnext) stage_write(cur ^ 1);

        __syncthreads();   // B3: S ready, next A/metadata ready

        // issue next tile's ah gather NOW (latency hides under tail + next MFMA1)
        if (hasnext) gather(cur ^ 1);

        // ---- per-tile segment metadata (redundant per wave, identical) ----
        int m_e = mis[cur][lane];
        int prevv = __shfl_up(m_e, 1);
        bool changed = (lane > 0) && (m_e != prevv);
        unsigned long long bmask = __ballot(changed);
        int segl = __popcll(bmask & ((2ull << lane) - 1ull));
        if (lane == 0 || changed) seg_atom[segl] = m_e;
        seg_lds[lane] = segl;
        int nseg = __popcll(bmask) + 1;

        // ---- selector MFMA: C[seg][f] = sel[seg][e] @ S[e][f] ----
        int myseg = 16 * wv + ln;
        bf16x8 sfr[2];
        #pragma unroll
        for (int ks = 0; ks < 2; ++ks) {
            const int* sp = &seg_lds[ks * 32 + l4 * 8];
            #pragma unroll
            for (int i = 0; i < 8; ++i)
                sfr[ks][i] = (sp[i] == myseg) ? (short)0x3F80 : (short)0;
        }
        f32x4 acc3[2] = {{0,0,0,0},{0,0,0,0}};
        #pragma unroll
        for (int ks = 0; ks < 2; ++ks) {
            #pragma unroll
            for (int nf = 0; nf < 2; ++nf) {
                bf16x8 b = *(const bf16x8*)&S_lds[(nf * 16 + ln) * 72 + ks * 32 + l4 * 8];
                acc3[nf] = __builtin_amdgcn_mfma_f32_16x16x32_bf16(sfr[ks], b, acc3[nf], 0, 0, 0);
            }
        }
        // ---- flush: one atomicAdd per (present segment, f) ----
        #pragma unroll
        for (int nf = 0; nf < 2; ++nf) {
            #pragma unroll
            for (int r = 0; r < 4; ++r) {
                int gs = 16 * wv + l4 * 4 + r;
                int f = nf * 16 + ln;
                if (gs < nseg && f < N_EMB) {
                    int atomId = seg_atom[gs];
                    atomicAdd(&out[(size_t)atomId * N_EMB + f], acc3[nf][r]);
                }
            }
        }
        cur ^= 1;
    }
}

extern "C" void kernel_launch(void* const* d_in, const int* in_sizes, int n_in,
                              void* d_out, int out_size, void* d_ws, size_t ws_size,
                              hipStream_t stream) {
    const float* af   = (const float*)d_in[0];
    const float* dist = (const float*)d_in[1];
    const int*   mi   = (const int*)d_in[2];
    const int*   mj   = (const int*)d_in[3];
    const float* W_cf = (const float*)d_in[4];
    const float* W_df = (const float*)d_in[5];
    const float* W_fc = (const float*)d_in[6];
    const float* b_cf = (const float*)d_in[7];
    const float* b_df = (const float*)d_in[8];
    float* out = (float*)d_out;
    ushort* ah_bf = (ushort*)d_ws;   // N_ATOMS * N_HID bf16 = 12 MB

    atom_kernel<<<N_ATOMS / 4, 256, 0, stream>>>(af, W_cf, W_fc, b_cf, b_df, ah_bf, out);
    edge_kernel<<<EBLOCKS, 256, 0, stream>>>(dist, mi, mj, W_df, W_fc, b_df, ah_bf, out);
}

// Round 8
// 299.970 us; speedup vs baseline: 1.4167x; 1.4167x over previous
//
#include <hip/hip_runtime.h>
#include <hip/hip_bf16.h>

#define N_ATOMS 100000
#define N_PAIRS 2000000
#define N_EMB 30
#define N_DIST 100
#define N_HID 60

#define TE 64                       // edges per tile
#define NTILES (N_PAIRS / TE)       // 31250 exact
#define EBLOCKS 768                 // 3 blocks/CU resident

typedef short bf16x8 __attribute__((ext_vector_type(8)));
typedef float f32x4 __attribute__((ext_vector_type(4)));

__device__ __forceinline__ ushort f2bf(float f) {
    __hip_bfloat16 h = __float2bfloat16(f);
    return __builtin_bit_cast(ushort, h);
}
__device__ __forceinline__ float bf2f(ushort u) {
    __hip_bfloat16 h = __builtin_bit_cast(__hip_bfloat16, u);
    return __bfloat162float(h);
}
__device__ __forceinline__ float fast_tanh(float x) {
    float e = __expf(2.0f * x);
    return 1.0f - 2.0f / (e + 1.0f);
}

// ---------------- Kernel A: per-atom hidden + output init ----------------
__global__ __launch_bounds__(256) void atom_kernel(
    const float* __restrict__ af, const float* __restrict__ W_cf,
    const float* __restrict__ W_fc, const float* __restrict__ b_cf,
    const float* __restrict__ b_df, float* __restrict__ ah_out,
    float* __restrict__ out)
{
    __shared__ __align__(16) float ah_lds[4][N_HID];
    const int wave = threadIdx.x >> 6;
    const int lane = threadIdx.x & 63;
    const int n = blockIdx.x * 4 + wave;

    float ahv = 0.f;
    if (lane < N_HID) {
        ahv = b_cf[lane];
        #pragma unroll
        for (int k = 0; k < N_EMB; ++k)
            ahv = fmaf(af[(size_t)n * N_EMB + k], W_cf[k * N_HID + lane], ahv);
        ah_out[(size_t)n * N_HID + lane] = ahv;
        ah_lds[wave][lane] = ahv * b_df[lane];
    }
    __syncthreads();
    if (lane < N_EMB) {
        float s = 0.f;
        #pragma unroll
        for (int h = 0; h < N_HID; ++h)
            s = fmaf(ah_lds[wave][h], W_fc[h * N_EMB + lane], s);
        out[(size_t)n * N_EMB + lane] =
            af[(size_t)n * N_EMB + lane] - fast_tanh(s);
    }
}

// ---------------- Kernel B: round-3 dbuf structure, gather-first + B1 removed ----------------
__global__ __launch_bounds__(256, 3) void edge_kernel(
    const float* __restrict__ dist,
    const int* __restrict__ mi, const int* __restrict__ mj,
    const float* __restrict__ W_df, const float* __restrict__ W_fc,
    const float* __restrict__ b_df, const float* __restrict__ ah,
    float* out)
{
    __shared__ ushort A_lds[2][TE * 136];     // 34816 B (double-buffered dist tile, bf16)
    __shared__ ushort T_lds[TE * 72];         // 9216 B
    __shared__ ushort S_lds[32 * 72];         // 4608 B  (S^T: [f][edge], stride 72)
    __shared__ int    mis[2][TE], mjs[2][TE]; // 1024 B
    __shared__ int    seg_lds[TE];            // 256 B
    __shared__ int    seg_atom[TE];           // 256 B

    const int tid = threadIdx.x;
    const int wv = tid >> 6, lane = tid & 63;
    const int l4 = lane >> 4, ln = lane & 15;
    const int h1 = wv * 16 + ln;              // stage-1 hid col for this lane

    // ---- one-time weight fragments ----
    bf16x8 wdf_hi[4], wdf_lo[4];              // B-frag: k = ks*32 + l4*8 + i, n = h1
    #pragma unroll
    for (int ks = 0; ks < 4; ++ks) {
        #pragma unroll
        for (int i = 0; i < 8; ++i) {
            int k = ks * 32 + l4 * 8 + i;
            float f = (k < N_DIST && h1 < N_HID) ? W_df[k * N_HID + h1] : 0.f;
            ushort hi = f2bf(f);
            wdf_hi[ks][i] = (short)hi;
            wdf_lo[ks][i] = (short)f2bf(f - bf2f(hi));
        }
    }
    bf16x8 wfc[2][2];                         // [nf][ks], single bf16
    #pragma unroll
    for (int nf = 0; nf < 2; ++nf) {
        #pragma unroll
        for (int ks = 0; ks < 2; ++ks) {
            #pragma unroll
            for (int i = 0; i < 8; ++i) {
                int k = ks * 32 + l4 * 8 + i;
                int n = nf * 16 + ln;
                float f = (k < N_HID && n < N_EMB) ? W_fc[k * N_EMB + n] : 0.f;
                wfc[nf][ks][i] = (short)f2bf(f);
            }
        }
    }
    const float bdf1 = (h1 < N_HID) ? b_df[h1] : 0.f;

    // zero A pad columns [100..136) in both buffers (never rewritten)
    for (int idx = tid; idx < 2 * TE * 36; idx += 256) {
        int b = idx / (TE * 36), rem = idx % (TE * 36);
        int r = rem / 36, c = 100 + rem % 36;
        A_lds[b][r * 136 + c] = 0;
    }

    const int t0 = (int)(((long long)blockIdx.x * NTILES) / EBLOCKS);
    const int t1 = (int)(((long long)(blockIdx.x + 1) * NTILES) / EBLOCKS);

    f32x4 pf[7];
    int pmi = 0, pmj = 0;

    auto stage_issue = [&](int t) {
        const f32x4* src = (const f32x4*)(dist + (size_t)t * TE * N_DIST);
        #pragma unroll
        for (int k = 0; k < 6; ++k)
            pf[k] = __builtin_nontemporal_load(&src[k * 256 + tid]);
        if (tid < 64) {
            pf[6] = __builtin_nontemporal_load(&src[6 * 256 + tid]);
            pmi = mi[t * TE + tid];
            pmj = mj[t * TE + tid];
        }
    };
    auto stage_write = [&](int buf) {
        #pragma unroll
        for (int k = 0; k < 7; ++k) {
            int idx = k * 256 + tid;
            if (k < 6 || tid < 64) {
                int r = idx / 25, c = idx % 25;
                f32x4 v = pf[k];
                ushort4 pk2;
                pk2.x = f2bf(v[0]); pk2.y = f2bf(v[1]);
                pk2.z = f2bf(v[2]); pk2.w = f2bf(v[3]);
                *(ushort4*)&A_lds[buf][r * 136 + c * 4] = pk2;
            }
        }
        if (tid < 64) { mis[buf][tid] = pmi; mjs[buf][tid] = pmj; }
    };

    // prologue: stage tile t0 into buffer 0
    stage_issue(t0);
    stage_write(0);
    __syncthreads();

    int cur = 0;
    for (int t = t0; t < t1; ++t) {
        const bool hasnext = (t + 1 < t1);

        // ---- gather FIRST: its waitcnt at the T-multiply must not drain the
        //      dist prefetch issued below (vmcnt counts youngest-N outstanding) ----
        float ahg[4][4];
        #pragma unroll
        for (int m = 0; m < 4; ++m) {
            #pragma unroll
            for (int r = 0; r < 4; ++r) {
                int el = 16 * m + l4 * 4 + r;
                int j = mjs[cur][el];
                ahg[m][r] = (h1 < N_HID) ? ah[(size_t)j * N_HID + h1] : 0.f;
            }
        }

        if (hasnext) stage_issue(t + 1);      // dist prefetch stays in flight past T-multiply

        // ---- stage-1 MFMA: 64 edges x 16 hids (hi/lo split) ----
        f32x4 acc1[4] = {{0,0,0,0},{0,0,0,0},{0,0,0,0},{0,0,0,0}};
        #pragma unroll
        for (int ks = 0; ks < 4; ++ks) {
            #pragma unroll
            for (int m = 0; m < 4; ++m) {
                bf16x8 a = *(const bf16x8*)&A_lds[cur][(16 * m + ln) * 136 + ks * 32 + l4 * 8];
                acc1[m] = __builtin_amdgcn_mfma_f32_16x16x32_bf16(a, wdf_hi[ks], acc1[m], 0, 0, 0);
                acc1[m] = __builtin_amdgcn_mfma_f32_16x16x32_bf16(a, wdf_lo[ks], acc1[m], 0, 0, 0);
            }
        }

        // (B1 removed: T-write(t) vs T-read(t-1) already separated by B3(t-1);
        //  A is double-buffered, no hazard)

        // ---- t = (dh + b_df) * ah -> bf16 -> T_lds ----
        #pragma unroll
        for (int m = 0; m < 4; ++m) {
            #pragma unroll
            for (int r = 0; r < 4; ++r) {
                int row = 16 * m + l4 * 4 + r;
                float tv = (acc1[m][r] + bdf1) * ahg[m][r];
                T_lds[row * 72 + h1] = (h1 < N_HID) ? f2bf(tv) : (ushort)0;
            }
        }
        __syncthreads();   // B2: T ready

        // ---- stage-2 MFMA: 16 edges x 32 f ----
        f32x4 acc2[2] = {{0,0,0,0},{0,0,0,0}};
        #pragma unroll
        for (int ks = 0; ks < 2; ++ks) {
            bf16x8 a2 = *(const bf16x8*)&T_lds[(16 * wv + ln) * 72 + ks * 32 + l4 * 8];
            #pragma unroll
            for (int nf = 0; nf < 2; ++nf)
                acc2[nf] = __builtin_amdgcn_mfma_f32_16x16x32_bf16(a2, wfc[nf][ks], acc2[nf], 0, 0, 0);
        }
        // tanh -> S^T (bf16); rows f>=30 exact zeros (wfc zero-padded)
        #pragma unroll
        for (int nf = 0; nf < 2; ++nf) {
            #pragma unroll
            for (int r = 0; r < 4; ++r) {
                int f = nf * 16 + ln;
                int e = 16 * wv + l4 * 4 + r;
                S_lds[f * 72 + e] = f2bf(fast_tanh(acc2[nf][r]));
            }
        }

        // write next tile's A while S settles
        if (hasnext) stage_write(cur ^ 1);

        __syncthreads();   // B3: S ready, next A ready

        // ---- per-tile segment metadata (redundant per wave, identical) ----
        int m_e = mis[cur][lane];
        int prevv = __shfl_up(m_e, 1);
        bool changed = (lane > 0) && (m_e != prevv);
        unsigned long long bmask = __ballot(changed);
        int segl = __popcll(bmask & ((2ull << lane) - 1ull));
        if (lane == 0 || changed) seg_atom[segl] = m_e;
        seg_lds[lane] = segl;
        int nseg = __popcll(bmask) + 1;

        // ---- selector MFMA: C[seg][f] = sel[seg][e] @ S[e][f] ----
        int myseg = 16 * wv + ln;
        bf16x8 sfr[2];
        #pragma unroll
        for (int ks = 0; ks < 2; ++ks) {
            const int* sp = &seg_lds[ks * 32 + l4 * 8];
            #pragma unroll
            for (int i = 0; i < 8; ++i)
                sfr[ks][i] = (sp[i] == myseg) ? (short)0x3F80 : (short)0;
        }
        f32x4 acc3[2] = {{0,0,0,0},{0,0,0,0}};
        #pragma unroll
        for (int ks = 0; ks < 2; ++ks) {
            #pragma unroll
            for (int nf = 0; nf < 2; ++nf) {
                bf16x8 b = *(const bf16x8*)&S_lds[(nf * 16 + ln) * 72 + ks * 32 + l4 * 8];
                acc3[nf] = __builtin_amdgcn_mfma_f32_16x16x32_bf16(sfr[ks], b, acc3[nf], 0, 0, 0);
            }
        }
        // ---- flush: one atomicAdd per (present segment, f) ----
        #pragma unroll
        for (int nf = 0; nf < 2; ++nf) {
            #pragma unroll
            for (int r = 0; r < 4; ++r) {
                int gs = 16 * wv + l4 * 4 + r;
                int f = nf * 16 + ln;
                if (gs < nseg && f < N_EMB) {
                    int atomId = seg_atom[gs];
                    atomicAdd(&out[(size_t)atomId * N_EMB + f], acc3[nf][r]);
                }
            }
        }
        cur ^= 1;
    }
}

extern "C" void kernel_launch(void* const* d_in, const int* in_sizes, int n_in,
                              void* d_out, int out_size, void* d_ws, size_t ws_size,
                              hipStream_t stream) {
    const float* af   = (const float*)d_in[0];
    const float* dist = (const float*)d_in[1];
    const int*   mi   = (const int*)d_in[2];
    const int*   mj   = (const int*)d_in[3];
    const float* W_cf = (const float*)d_in[4];
    const float* W_df = (const float*)d_in[5];
    const float* W_fc = (const float*)d_in[6];
    const float* b_cf = (const float*)d_in[7];
    const float* b_df = (const float*)d_in[8];
    float* out = (float*)d_out;
    float* ah  = (float*)d_ws;   // N_ATOMS * N_HID floats = 24 MB

    atom_kernel<<<N_ATOMS / 4, 256, 0, stream>>>(af, W_cf, W_fc, b_cf, b_df, ah, out);
    edge_kernel<<<EBLOCKS, 256, 0, stream>>>(dist, mi, mj, W_df, W_fc, b_df, ah, out);
}